// Round 7
// baseline (470.952 us; speedup 1.0000x reference)
//
#include <hip/hip_runtime.h>
#include <hip/hip_fp16.h>

#define N_NODES 100000
#define E_EDGES 1600000
#define E4 (E_EDGES / 4)                       // 400000
#define NBUCKETS ((N_NODES + 127) / 128)       // 782
#define CHUNK 8192
#define NCHUNK ((E_EDGES + CHUNK - 1) / CHUNK) // 196
#define HM (NBUCKETS * NCHUNK)                 // 153272
#define NSB ((HM + 1023) / 1024)               // 150

// ---------------------------------------------------------------------------
// Proven round-5 agg inner loop as a helper (unroll x8 -> x4 -> x1).
// Returns acc += sum_k w_k * Hin[src_k * HSTRIDE + lane] for k in [k0,k1).
// ---------------------------------------------------------------------------
template<int HSTRIDE>
__device__ __forceinline__ float agg_edges(const __half* __restrict__ Hin,
                                           const int2* __restrict__ csr,
                                           int k0, int k1, int lane, bool active,
                                           float acc) {
    int k = k0;
    for (; k + 7 < k1; k += 8) {
        int2 e[8];
#pragma unroll
        for (int u = 0; u < 8; ++u) e[u] = csr[k + u];
        float h[8];
#pragma unroll
        for (int u = 0; u < 8; ++u) {
            int s = __builtin_amdgcn_readfirstlane(e[u].x);
            h[u] = active ? __half2float(Hin[(size_t)s * HSTRIDE + lane]) : 0.f;
        }
#pragma unroll
        for (int u = 0; u < 8; ++u) acc += h[u] * __int_as_float(e[u].y);
    }
    for (; k + 3 < k1; k += 4) {
        int2 e0 = csr[k], e1 = csr[k + 1], e2 = csr[k + 2], e3 = csr[k + 3];
        int s0 = __builtin_amdgcn_readfirstlane(e0.x);
        int s1 = __builtin_amdgcn_readfirstlane(e1.x);
        int s2 = __builtin_amdgcn_readfirstlane(e2.x);
        int s3 = __builtin_amdgcn_readfirstlane(e3.x);
        float h0 = 0.f, h1 = 0.f, h2 = 0.f, h3 = 0.f;
        if (active) {
            h0 = __half2float(Hin[(size_t)s0 * HSTRIDE + lane]);
            h1 = __half2float(Hin[(size_t)s1 * HSTRIDE + lane]);
            h2 = __half2float(Hin[(size_t)s2 * HSTRIDE + lane]);
            h3 = __half2float(Hin[(size_t)s3 * HSTRIDE + lane]);
        }
        acc += h0 * __int_as_float(e0.y) + h1 * __int_as_float(e1.y)
             + h2 * __int_as_float(e2.y) + h3 * __int_as_float(e3.y);
    }
    for (; k < k1; ++k) {
        int2 e0 = csr[k];
        int s0 = __builtin_amdgcn_readfirstlane(e0.x);
        if (active) acc += __half2float(Hin[(size_t)s0 * HSTRIDE + lane]) * __int_as_float(e0.y);
    }
    return acc;
}

// ---------------------------------------------------------------------------
// GEMM (round-5 proven): H[N,DOUT] = X[N,64] @ W[64,DOUT], fp16 output
// ---------------------------------------------------------------------------
template<int DOUT>
__global__ __launch_bounds__(256) void gemm_tile(const float* __restrict__ X,
                                                 const float* __restrict__ W,
                                                 __half* __restrict__ H) {
    __shared__ float Xs[64][68];
    __shared__ float Ws[64 * DOUT];
    const int tid = threadIdx.x;

    for (int i = tid; i < 64 * DOUT / 4; i += 256) {
        reinterpret_cast<float4*>(Ws)[i] = reinterpret_cast<const float4*>(W)[i];
    }

    const int row0 = blockIdx.x * 64;
#pragma unroll
    for (int p = 0; p < 4; ++p) {
        int idx = p * 256 + tid;
        int r = idx >> 4;
        int c = (idx & 15) << 2;
        float4 v = make_float4(0.f, 0.f, 0.f, 0.f);
        if (row0 + r < N_NODES) {
            v = *reinterpret_cast<const float4*>(X + (size_t)(row0 + r) * 64 + c);
        }
        *reinterpret_cast<float4*>(&Xs[r][c]) = v;
    }
    __syncthreads();

    const int tr = (tid >> 4) << 2;
    const int tc = (tid & 15) << 2;
    if (tc < DOUT) {
        float acc[4][4];
#pragma unroll
        for (int i = 0; i < 4; ++i)
#pragma unroll
            for (int j = 0; j < 4; ++j) acc[i][j] = 0.f;

#pragma unroll 8
        for (int k = 0; k < 64; ++k) {
            float4 wv = *reinterpret_cast<const float4*>(&Ws[k * DOUT + tc]);
            float xv[4];
#pragma unroll
            for (int i = 0; i < 4; ++i) xv[i] = Xs[tr + i][k];
#pragma unroll
            for (int i = 0; i < 4; ++i) {
                acc[i][0] += xv[i] * wv.x;
                acc[i][1] += xv[i] * wv.y;
                acc[i][2] += xv[i] * wv.z;
                acc[i][3] += xv[i] * wv.w;
            }
        }
#pragma unroll
        for (int i = 0; i < 4; ++i) {
            int r = row0 + tr + i;
            if (r < N_NODES) {
                union { __half2 h2[2]; uint2 u; } pk;
                pk.h2[0] = __halves2half2(__float2half(acc[i][0]), __float2half(acc[i][1]));
                pk.h2[1] = __halves2half2(__float2half(acc[i][2]), __float2half(acc[i][3]));
                *reinterpret_cast<uint2*>(H + (size_t)r * DOUT + tc) = pk.u;
            }
        }
    }
}

// ---------------------------------------------------------------------------
// FUSED: A = agg(Hin)+bprev; X = relu(A); Hout = X @ W  (fp16 out)
// 512 threads = 8 waves; 128 nodes/block. Phase 1: one wave per node
// (proven agg loop) -> LDS Xs. Phase 2: proven gemm compute on Xs.
// ---------------------------------------------------------------------------
template<int DOUT>
__global__ __launch_bounds__(512) void fused_agg_gemm(const __half* __restrict__ Hin,
                                                      const int* __restrict__ off,
                                                      const int2* __restrict__ csr,
                                                      const float* __restrict__ bprev,
                                                      const float* __restrict__ W,
                                                      __half* __restrict__ Hout) {
    __shared__ float Xs[128][68];
    __shared__ float Ws[64 * DOUT];
    const int tid = threadIdx.x;
    const int lane = tid & 63;
    const int wv = tid >> 6;                  // 0..7
    const int row0 = blockIdx.x * 128;

    for (int i = tid; i < 64 * DOUT / 4; i += 512) {
        reinterpret_cast<float4*>(Ws)[i] = reinterpret_cast<const float4*>(W)[i];
    }

    const float bias = bprev[lane];           // prev conv is 64-wide

    // ---- phase 1: aggregate 128 nodes (one wave per node, 16 iters) ----
#pragma unroll 1
    for (int it = 0; it < 16; ++it) {
        const int nodeIdx = wv + it * 8;      // 0..127
        const int node = row0 + nodeIdx;
        if (node < N_NODES) {
            const int k0 = __builtin_amdgcn_readfirstlane(off[node]);
            const int k1 = __builtin_amdgcn_readfirstlane(off[node + 1]);
            float acc = agg_edges<64>(Hin, csr, k0, k1, lane, true, bias);
            Xs[nodeIdx][lane] = fmaxf(acc, 0.f);
        }
    }
    __syncthreads();

    // ---- phase 2: gemm (512 threads cover 128x64 outputs, 4x4 each) ----
    const int tr = (tid >> 4) << 2;           // 0..124
    const int tc = (tid & 15) << 2;           // 0..60
    if (tc < DOUT) {
        float acc[4][4];
#pragma unroll
        for (int i = 0; i < 4; ++i)
#pragma unroll
            for (int j = 0; j < 4; ++j) acc[i][j] = 0.f;

#pragma unroll 8
        for (int k = 0; k < 64; ++k) {
            float4 wvv = *reinterpret_cast<const float4*>(&Ws[k * DOUT + tc]);
            float xv[4];
#pragma unroll
            for (int i = 0; i < 4; ++i) xv[i] = Xs[tr + i][k];
#pragma unroll
            for (int i = 0; i < 4; ++i) {
                acc[i][0] += xv[i] * wvv.x;
                acc[i][1] += xv[i] * wvv.y;
                acc[i][2] += xv[i] * wvv.z;
                acc[i][3] += xv[i] * wvv.w;
            }
        }
#pragma unroll
        for (int i = 0; i < 4; ++i) {
            int r = row0 + tr + i;
            if (r < N_NODES) {
                union { __half2 h2[2]; uint2 u; } pk;
                pk.h2[0] = __halves2half2(__float2half(acc[i][0]), __float2half(acc[i][1]));
                pk.h2[1] = __halves2half2(__float2half(acc[i][2]), __float2half(acc[i][3]));
                *reinterpret_cast<uint2*>(Hout + (size_t)r * DOUT + tc) = pk.u;
            }
        }
    }
}

// ---------------------------------------------------------------------------
// Final standalone aggregate (DOUT=40): out = agg(Hin) + bout  (fp32 out)
// ---------------------------------------------------------------------------
template<int DOUT>
__global__ __launch_bounds__(256) void aggregate(const __half* __restrict__ H,
                                                 const int* __restrict__ off,
                                                 const int2* __restrict__ csr,
                                                 const float* __restrict__ bvec,
                                                 float* __restrict__ AGG) {
    const int node = (int)((blockIdx.x * 256 + threadIdx.x) >> 6);
    const int lane = threadIdx.x & 63;
    if (node >= N_NODES) return;
    const int k0 = __builtin_amdgcn_readfirstlane(off[node]);
    const int k1 = __builtin_amdgcn_readfirstlane(off[node + 1]);
    const bool active = (DOUT == 64) || (lane < DOUT);
    float acc = active ? bvec[lane] : 0.f;
    acc = agg_edges<DOUT>(H, csr, k0, k1, lane, active, acc);
    if (active) AGG[(size_t)node * DOUT + lane] = acc;
}

// ---------------------------------------------------------------------------
// CSR build v3 (round-5 proven): chunked counting sort, NO global atomics.
// ---------------------------------------------------------------------------
__global__ __launch_bounds__(256) void chunk_hist(const int4* __restrict__ dst4,
                                                  int* __restrict__ histM) {
    __shared__ int lh[NBUCKETS];
    const int tid = threadIdx.x, c = blockIdx.x;
    for (int i = tid; i < NBUCKETS; i += 256) lh[i] = 0;
    __syncthreads();
    const int q0 = c * (CHUNK / 4);
    for (int q = tid; q < CHUNK / 4; q += 256) {
        if (q0 + q < E4) {
            int4 d = dst4[q0 + q];
            atomicAdd(&lh[d.x >> 7], 1);
            atomicAdd(&lh[d.y >> 7], 1);
            atomicAdd(&lh[d.z >> 7], 1);
            atomicAdd(&lh[d.w >> 7], 1);
        }
    }
    __syncthreads();
    for (int i = tid; i < NBUCKETS; i += 256) histM[i * NCHUNK + c] = lh[i];
}

__global__ __launch_bounds__(256) void scan_blocks(const int* __restrict__ in,
                                                   int* __restrict__ out,
                                                   int* __restrict__ bsums) {
    __shared__ int wsum[4];
    const int tid = threadIdx.x, lane = tid & 63, wv = tid >> 6;
    const int base = blockIdx.x * 1024 + tid * 4;
    int v[4];
    int s = 0;
#pragma unroll
    for (int j = 0; j < 4; ++j) {
        v[j] = (base + j < HM) ? in[base + j] : 0;
        s += v[j];
    }
    int inc = s;
#pragma unroll
    for (int o = 1; o < 64; o <<= 1) {
        int t = __shfl_up(inc, o, 64);
        if (lane >= o) inc += t;
    }
    if (lane == 63) wsum[wv] = inc;
    __syncthreads();
    int woff = 0;
    for (int w2 = 0; w2 < wv; ++w2) woff += wsum[w2];
    int run = woff + inc - s;
#pragma unroll
    for (int j = 0; j < 4; ++j) {
        if (base + j < HM) out[base + j] = run;
        run += v[j];
    }
    if (tid == 255) bsums[blockIdx.x] = woff + inc;
}

__global__ __launch_bounds__(256) void scan_mid256(const int* __restrict__ bs,
                                                   int* __restrict__ boff) {
    __shared__ int wsum[4];
    const int tid = threadIdx.x, lane = tid & 63, wv = tid >> 6;
    int v = (tid < NSB) ? bs[tid] : 0;
    int inc = v;
#pragma unroll
    for (int o = 1; o < 64; o <<= 1) {
        int t = __shfl_up(inc, o, 64);
        if (lane >= o) inc += t;
    }
    if (lane == 63) wsum[wv] = inc;
    __syncthreads();
    int woff = 0;
    for (int w2 = 0; w2 < wv; ++w2) woff += wsum[w2];
    if (tid < NSB) boff[tid] = woff + inc - v;
}

__global__ __launch_bounds__(256) void scan_add(int* __restrict__ out,
                                                const int* __restrict__ boff) {
    const int base = blockIdx.x * 1024 + threadIdx.x * 4;
    const int a = boff[blockIdx.x];
#pragma unroll
    for (int j = 0; j < 4; ++j) {
        if (base + j < HM) out[base + j] += a;
    }
}

__global__ __launch_bounds__(256) void chunk_scatter(const int4* __restrict__ src4,
                                                     const int4* __restrict__ dst4,
                                                     const float4* __restrict__ ew4,
                                                     const int* __restrict__ hs,
                                                     int2* __restrict__ tmp) {
    __shared__ int lcur[NBUCKETS];
    const int tid = threadIdx.x, c = blockIdx.x;
    for (int i = tid; i < NBUCKETS; i += 256) lcur[i] = hs[i * NCHUNK + c];
    __syncthreads();
    const int q0 = c * (CHUNK / 4);
    for (int q = tid; q < CHUNK / 4; q += 256) {
        if (q0 + q < E4) {
            int4 s = src4[q0 + q];
            int4 d = dst4[q0 + q];
            float4 w = ew4[q0 + q];
            int p0 = atomicAdd(&lcur[d.x >> 7], 1);
            tmp[p0] = make_int2(s.x | ((d.x & 127) << 17), __float_as_int(w.x));
            int p1 = atomicAdd(&lcur[d.y >> 7], 1);
            tmp[p1] = make_int2(s.y | ((d.y & 127) << 17), __float_as_int(w.y));
            int p2 = atomicAdd(&lcur[d.z >> 7], 1);
            tmp[p2] = make_int2(s.z | ((d.z & 127) << 17), __float_as_int(w.z));
            int p3 = atomicAdd(&lcur[d.w >> 7], 1);
            tmp[p3] = make_int2(s.w | ((d.w & 127) << 17), __float_as_int(w.w));
        }
    }
}

__global__ __launch_bounds__(256) void build_csr(const int2* __restrict__ tmp,
                                                 const int* __restrict__ hs,
                                                 int* __restrict__ off,
                                                 int2* __restrict__ csr) {
    __shared__ int lhist[128];
    __shared__ int lcur[128];
    __shared__ int wtot[4];
    const int b = blockIdx.x;
    const int tid = threadIdx.x, lane = tid & 63, wv = tid >> 6;
    const int base = hs[b * NCHUNK];
    const int end  = (b + 1 < NBUCKETS) ? hs[(b + 1) * NCHUNK] : E_EDGES;

    if (tid < 128) lhist[tid] = 0;
    __syncthreads();

    for (int e = base + tid; e < end; e += 256) {
        int dl = (tmp[e].x >> 17) & 127;
        atomicAdd(&lhist[dl], 1);
    }
    __syncthreads();

    int v = (tid < 128) ? lhist[tid] : 0;
    int inc = v;
#pragma unroll
    for (int o = 1; o < 64; o <<= 1) {
        int t = __shfl_up(inc, o, 64);
        if (lane >= o) inc += t;
    }
    if (lane == 63) wtot[wv] = inc;
    __syncthreads();
    if (tid < 128) {
        int excl = inc - v + ((wv == 1) ? wtot[0] : 0);
        lcur[tid] = base + excl;
        int node = b * 128 + tid;
        if (node < N_NODES) off[node] = base + excl;
    }
    if (b == NBUCKETS - 1 && tid == 0) off[N_NODES] = E_EDGES;
    __syncthreads();

    for (int e = base + tid; e < end; e += 256) {
        int2 t2 = tmp[e];
        int dl = (t2.x >> 17) & 127;
        int p = atomicAdd(&lcur[dl], 1);
        csr[p] = make_int2(t2.x & 0x1FFFF, t2.y);
    }
}

// ---------------------------------------------------------------------------
extern "C" void kernel_launch(void* const* d_in, const int* in_sizes, int n_in,
                              void* d_out, int out_size, void* d_ws, size_t ws_size,
                              hipStream_t stream) {
    const float* x    = (const float*)d_in[0];
    const float* ew   = (const float*)d_in[1];
    const float* W    = (const float*)d_in[2];   // [4,64,64]
    const float* b    = (const float*)d_in[3];   // [4,64]
    const float* Wout = (const float*)d_in[4];   // [64,40]
    const float* bout = (const float*)d_in[5];   // [40]
    const int*   src  = (const int*)d_in[6];
    const int*   dst  = (const int*)d_in[7];
    float* out = (float*)d_out;

    // workspace layout (all regions disjoint)
    char* wsp = (char*)d_ws;
    size_t  o   = 0;
    __half* HA  = (__half*)(wsp + o); o += (size_t)N_NODES * 64 * sizeof(__half); // 12.8 MB
    __half* HB  = (__half*)(wsp + o); o += (size_t)N_NODES * 64 * sizeof(__half); // 12.8 MB
    int2*   csr = (int2*)(wsp + o);   o += (size_t)E_EDGES * sizeof(int2);        // 12.8 MB
    int2*   tmp = (int2*)(wsp + o);   o += (size_t)E_EDGES * sizeof(int2);        // 12.8 MB
    int*    off = (int*)(wsp + o);    o += (size_t)(N_NODES + 1) * sizeof(int);
    int*  histM = (int*)(wsp + o);    o += (size_t)HM * sizeof(int);
    int*    hs  = (int*)(wsp + o);    o += (size_t)HM * sizeof(int);
    int*  bsums = (int*)(wsp + o);    o += (size_t)NSB * sizeof(int);
    int*   boff = (int*)(wsp + o);    o += (size_t)NSB * sizeof(int);

    dim3 blk(256);
    const int gemmGrid  = (N_NODES + 63) / 64;             // 1563
    const int fusedGrid = (N_NODES + 127) / 128;           // 782
    const int aggGrid   = (N_NODES * 64 + 255) / 256;      // 25000

    // ---- build CSR (once; reused by all 5 layers), zero global atomics ----
    chunk_hist<<<NCHUNK, blk, 0, stream>>>((const int4*)dst, histM);
    scan_blocks<<<NSB, blk, 0, stream>>>(histM, hs, bsums);
    scan_mid256<<<1, blk, 0, stream>>>(bsums, boff);
    scan_add<<<NSB, blk, 0, stream>>>(hs, boff);
    chunk_scatter<<<NCHUNK, blk, 0, stream>>>((const int4*)src, (const int4*)dst,
                                              (const float4*)ew, hs, tmp);
    build_csr<<<NBUCKETS, blk, 0, stream>>>(tmp, hs, off, csr);

    // ---- layer 0 gemm: HA = x @ W0 ----
    gemm_tile<64><<<gemmGrid, blk, 0, stream>>>(x, W, HA);

    // ---- fused interior: agg + bias + relu + gemm ----
    fused_agg_gemm<64><<<fusedGrid, 512, 0, stream>>>(HA, off, csr, b,          W + 1 * 4096, HB);
    fused_agg_gemm<64><<<fusedGrid, 512, 0, stream>>>(HB, off, csr, b + 64,     W + 2 * 4096, HA);
    fused_agg_gemm<64><<<fusedGrid, 512, 0, stream>>>(HA, off, csr, b + 128,    W + 3 * 4096, HB);
    fused_agg_gemm<40><<<fusedGrid, 512, 0, stream>>>(HB, off, csr, b + 192,    Wout,         HA);

    // ---- final aggregate -> d_out [N,40] ----
    aggregate<40><<<aggGrid, blk, 0, stream>>>(HA, off, csr, bout, out);
}

// Round 8
// 414.926 us; speedup vs baseline: 1.1350x; 1.1350x over previous
//
#include <hip/hip_runtime.h>
#include <hip/hip_fp16.h>

#define N_NODES 100000
#define E_EDGES 1600000
#define E4 (E_EDGES / 4)                       // 400000
#define NBUCKETS ((N_NODES + 127) / 128)       // 782
#define CHUNK 8192
#define NCHUNK ((E_EDGES + CHUNK - 1) / CHUNK) // 196
#define HM (NBUCKETS * NCHUNK)                 // 153272
#define NSB ((HM + 1023) / 1024)               // 150

// ---------------------------------------------------------------------------
// GEMM (round-5 proven): H[N,DOUT] = act(X)[N,64] @ W[64,DOUT], fp16 output
// ---------------------------------------------------------------------------
template<int DOUT, bool RELU_IN>
__global__ __launch_bounds__(256) void gemm_tile(const float* __restrict__ X,
                                                 const float* __restrict__ W,
                                                 __half* __restrict__ H) {
    __shared__ float Xs[64][68];
    __shared__ float Ws[64 * DOUT];
    const int tid = threadIdx.x;

    for (int i = tid; i < 64 * DOUT / 4; i += 256) {
        reinterpret_cast<float4*>(Ws)[i] = reinterpret_cast<const float4*>(W)[i];
    }

    const int row0 = blockIdx.x * 64;
#pragma unroll
    for (int p = 0; p < 4; ++p) {
        int idx = p * 256 + tid;
        int r = idx >> 4;
        int c = (idx & 15) << 2;
        float4 v = make_float4(0.f, 0.f, 0.f, 0.f);
        if (row0 + r < N_NODES) {
            v = *reinterpret_cast<const float4*>(X + (size_t)(row0 + r) * 64 + c);
        }
        if (RELU_IN) {
            v.x = fmaxf(v.x, 0.f); v.y = fmaxf(v.y, 0.f);
            v.z = fmaxf(v.z, 0.f); v.w = fmaxf(v.w, 0.f);
        }
        *reinterpret_cast<float4*>(&Xs[r][c]) = v;
    }
    __syncthreads();

    const int tr = (tid >> 4) << 2;
    const int tc = (tid & 15) << 2;
    if (tc < DOUT) {
        float acc[4][4];
#pragma unroll
        for (int i = 0; i < 4; ++i)
#pragma unroll
            for (int j = 0; j < 4; ++j) acc[i][j] = 0.f;

#pragma unroll 8
        for (int k = 0; k < 64; ++k) {
            float4 wv = *reinterpret_cast<const float4*>(&Ws[k * DOUT + tc]);
            float xv[4];
#pragma unroll
            for (int i = 0; i < 4; ++i) xv[i] = Xs[tr + i][k];
#pragma unroll
            for (int i = 0; i < 4; ++i) {
                acc[i][0] += xv[i] * wv.x;
                acc[i][1] += xv[i] * wv.y;
                acc[i][2] += xv[i] * wv.z;
                acc[i][3] += xv[i] * wv.w;
            }
        }
#pragma unroll
        for (int i = 0; i < 4; ++i) {
            int r = row0 + tr + i;
            if (r < N_NODES) {
                union { __half2 h2[2]; uint2 u; } pk;
                pk.h2[0] = __halves2half2(__float2half(acc[i][0]), __float2half(acc[i][1]));
                pk.h2[1] = __halves2half2(__float2half(acc[i][2]), __float2half(acc[i][3]));
                *reinterpret_cast<uint2*>(H + (size_t)r * DOUT + tc) = pk.u;
            }
        }
    }
}

// ---------------------------------------------------------------------------
// CSR build v3: chunked counting sort, NO global atomics. (round-5 proven)
// ---------------------------------------------------------------------------
__global__ __launch_bounds__(256) void chunk_hist(const int4* __restrict__ dst4,
                                                  int* __restrict__ histM) {
    __shared__ int lh[NBUCKETS];
    const int tid = threadIdx.x, c = blockIdx.x;
    for (int i = tid; i < NBUCKETS; i += 256) lh[i] = 0;
    __syncthreads();
    const int q0 = c * (CHUNK / 4);
    for (int q = tid; q < CHUNK / 4; q += 256) {
        if (q0 + q < E4) {
            int4 d = dst4[q0 + q];
            atomicAdd(&lh[d.x >> 7], 1);
            atomicAdd(&lh[d.y >> 7], 1);
            atomicAdd(&lh[d.z >> 7], 1);
            atomicAdd(&lh[d.w >> 7], 1);
        }
    }
    __syncthreads();
    for (int i = tid; i < NBUCKETS; i += 256) histM[i * NCHUNK + c] = lh[i];
}

__global__ __launch_bounds__(256) void scan_blocks(const int* __restrict__ in,
                                                   int* __restrict__ out,
                                                   int* __restrict__ bsums) {
    __shared__ int wsum[4];
    const int tid = threadIdx.x, lane = tid & 63, wv = tid >> 6;
    const int base = blockIdx.x * 1024 + tid * 4;
    int v[4];
    int s = 0;
#pragma unroll
    for (int j = 0; j < 4; ++j) {
        v[j] = (base + j < HM) ? in[base + j] : 0;
        s += v[j];
    }
    int inc = s;
#pragma unroll
    for (int o = 1; o < 64; o <<= 1) {
        int t = __shfl_up(inc, o, 64);
        if (lane >= o) inc += t;
    }
    if (lane == 63) wsum[wv] = inc;
    __syncthreads();
    int woff = 0;
    for (int w2 = 0; w2 < wv; ++w2) woff += wsum[w2];
    int run = woff + inc - s;
#pragma unroll
    for (int j = 0; j < 4; ++j) {
        if (base + j < HM) out[base + j] = run;
        run += v[j];
    }
    if (tid == 255) bsums[blockIdx.x] = woff + inc;
}

__global__ __launch_bounds__(256) void scan_mid256(const int* __restrict__ bs,
                                                   int* __restrict__ boff) {
    __shared__ int wsum[4];
    const int tid = threadIdx.x, lane = tid & 63, wv = tid >> 6;
    int v = (tid < NSB) ? bs[tid] : 0;
    int inc = v;
#pragma unroll
    for (int o = 1; o < 64; o <<= 1) {
        int t = __shfl_up(inc, o, 64);
        if (lane >= o) inc += t;
    }
    if (lane == 63) wsum[wv] = inc;
    __syncthreads();
    int woff = 0;
    for (int w2 = 0; w2 < wv; ++w2) woff += wsum[w2];
    if (tid < NSB) boff[tid] = woff + inc - v;
}

__global__ __launch_bounds__(256) void scan_add(int* __restrict__ out,
                                                const int* __restrict__ boff) {
    const int base = blockIdx.x * 1024 + threadIdx.x * 4;
    const int a = boff[blockIdx.x];
#pragma unroll
    for (int j = 0; j < 4; ++j) {
        if (base + j < HM) out[base + j] += a;
    }
}

__global__ __launch_bounds__(256) void chunk_scatter(const int4* __restrict__ src4,
                                                     const int4* __restrict__ dst4,
                                                     const float4* __restrict__ ew4,
                                                     const int* __restrict__ hs,
                                                     int2* __restrict__ tmp) {
    __shared__ int lcur[NBUCKETS];
    const int tid = threadIdx.x, c = blockIdx.x;
    for (int i = tid; i < NBUCKETS; i += 256) lcur[i] = hs[i * NCHUNK + c];
    __syncthreads();
    const int q0 = c * (CHUNK / 4);
    for (int q = tid; q < CHUNK / 4; q += 256) {
        if (q0 + q < E4) {
            int4 s = src4[q0 + q];
            int4 d = dst4[q0 + q];
            float4 w = ew4[q0 + q];
            int p0 = atomicAdd(&lcur[d.x >> 7], 1);
            tmp[p0] = make_int2(s.x | ((d.x & 127) << 17), __float_as_int(w.x));
            int p1 = atomicAdd(&lcur[d.y >> 7], 1);
            tmp[p1] = make_int2(s.y | ((d.y & 127) << 17), __float_as_int(w.y));
            int p2 = atomicAdd(&lcur[d.z >> 7], 1);
            tmp[p2] = make_int2(s.z | ((d.z & 127) << 17), __float_as_int(w.z));
            int p3 = atomicAdd(&lcur[d.w >> 7], 1);
            tmp[p3] = make_int2(s.w | ((d.w & 127) << 17), __float_as_int(w.w));
        }
    }
}

__global__ __launch_bounds__(256) void build_csr(const int2* __restrict__ tmp,
                                                 const int* __restrict__ hs,
                                                 int* __restrict__ off,
                                                 int2* __restrict__ csr) {
    __shared__ int lhist[128];
    __shared__ int lcur[128];
    __shared__ int wtot[4];
    const int b = blockIdx.x;
    const int tid = threadIdx.x, lane = tid & 63, wv = tid >> 6;
    const int base = hs[b * NCHUNK];
    const int end  = (b + 1 < NBUCKETS) ? hs[(b + 1) * NCHUNK] : E_EDGES;

    if (tid < 128) lhist[tid] = 0;
    __syncthreads();

    for (int e = base + tid; e < end; e += 256) {
        int dl = (tmp[e].x >> 17) & 127;
        atomicAdd(&lhist[dl], 1);
    }
    __syncthreads();

    int v = (tid < 128) ? lhist[tid] : 0;
    int inc = v;
#pragma unroll
    for (int o = 1; o < 64; o <<= 1) {
        int t = __shfl_up(inc, o, 64);
        if (lane >= o) inc += t;
    }
    if (lane == 63) wtot[wv] = inc;
    __syncthreads();
    if (tid < 128) {
        int excl = inc - v + ((wv == 1) ? wtot[0] : 0);
        lcur[tid] = base + excl;
        int node = b * 128 + tid;
        if (node < N_NODES) off[node] = base + excl;
    }
    if (b == NBUCKETS - 1 && tid == 0) off[N_NODES] = E_EDGES;
    __syncthreads();

    for (int e = base + tid; e < end; e += 256) {
        int2 t2 = tmp[e];
        int dl = (t2.x >> 17) & 127;
        int p = atomicAdd(&lcur[dl], 1);
        csr[p] = make_int2(t2.x & 0x1FFFF, t2.y);
    }
}

// ---------------------------------------------------------------------------
// Aggregate v3: one wave per dst node. Lanes 0-31 process even edges, lanes
// 32-63 odd edges; each lane handles 2 channels via __half2. 8 edges in
// flight per batch (2 rows per gather instr). Scalar (SGPR) loop bounds.
// Cross-half __shfl_xor reduce at the end.
// ---------------------------------------------------------------------------
template<int DOUT>
__global__ __launch_bounds__(256) void aggregate(const __half* __restrict__ H,
                                                 const int* __restrict__ off,
                                                 const int2* __restrict__ csr,
                                                 const float* __restrict__ bvec,
                                                 float* __restrict__ AGG) {
    const int node = (int)((blockIdx.x * 256 + threadIdx.x) >> 6);
    const int lane = threadIdx.x & 63;
    if (node >= N_NODES) return;
    const int half_id = lane >> 5;            // 0: even edges, 1: odd edges
    const int c = lane & 31;                  // channel pair: 2c, 2c+1
    const int k0 = __builtin_amdgcn_readfirstlane(off[node]);
    const int k1 = __builtin_amdgcn_readfirstlane(off[node + 1]);

    float accx = 0.f, accy = 0.f;
    int k = k0;
    for (; k + 7 < k1; k += 8) {
        // 4 metadata loads, each covers 2 edges (one per wave-half)
        int2 e0 = csr[k + 0 + half_id];
        int2 e1 = csr[k + 2 + half_id];
        int2 e2 = csr[k + 4 + half_id];
        int2 e3 = csr[k + 6 + half_id];
        // 4 gathers, each instr reads 2 rows (half2 = 2 channels per lane)
        float2 h0 = __half22float2(*reinterpret_cast<const __half2*>(H + (size_t)e0.x * DOUT + 2 * c));
        float2 h1 = __half22float2(*reinterpret_cast<const __half2*>(H + (size_t)e1.x * DOUT + 2 * c));
        float2 h2 = __half22float2(*reinterpret_cast<const __half2*>(H + (size_t)e2.x * DOUT + 2 * c));
        float2 h3 = __half22float2(*reinterpret_cast<const __half2*>(H + (size_t)e3.x * DOUT + 2 * c));
        float w0 = __int_as_float(e0.y), w1 = __int_as_float(e1.y);
        float w2 = __int_as_float(e2.y), w3 = __int_as_float(e3.y);
        accx += h0.x * w0 + h1.x * w1 + h2.x * w2 + h3.x * w3;
        accy += h0.y * w0 + h1.y * w1 + h2.y * w2 + h3.y * w3;
    }
    // tail: 2 edges per step (one per half), predicated
    for (; k < k1; k += 2) {
        const int kk = k + half_id;
        const bool vld = kk < k1;
        int2 e = csr[vld ? kk : k];
        float2 h = make_float2(0.f, 0.f);
        if (vld) {
            h = __half22float2(*reinterpret_cast<const __half2*>(H + (size_t)e.x * DOUT + 2 * c));
            float w = __int_as_float(e.y);
            accx += h.x * w;
            accy += h.y * w;
        }
    }
    // fold odd-edge half into even-edge half
    accx += __shfl_xor(accx, 32);
    accy += __shfl_xor(accy, 32);

    if (half_id == 0 && 2 * c < DOUT) {
        float2 st = make_float2(accx + bvec[2 * c], accy + bvec[2 * c + 1]);
        *reinterpret_cast<float2*>(AGG + (size_t)node * DOUT + 2 * c) = st;
    }
}

// ---------------------------------------------------------------------------
extern "C" void kernel_launch(void* const* d_in, const int* in_sizes, int n_in,
                              void* d_out, int out_size, void* d_ws, size_t ws_size,
                              hipStream_t stream) {
    const float* x    = (const float*)d_in[0];
    const float* ew   = (const float*)d_in[1];
    const float* W    = (const float*)d_in[2];   // [4,64,64]
    const float* b    = (const float*)d_in[3];   // [4,64]
    const float* Wout = (const float*)d_in[4];   // [64,40]
    const float* bout = (const float*)d_in[5];   // [40]
    const int*   src  = (const int*)d_in[6];
    const int*   dst  = (const int*)d_in[7];
    float* out = (float*)d_out;

    // workspace layout (tmp aliases H2: tmp fully consumed by build_csr
    // before the first gemm writes H2; stream order guarantees this)
    char* wsp = (char*)d_ws;
    __half* H2  = (__half*)wsp;                                   // N*64 half (12.8 MB)
    int2*   tmp = (int2*)wsp;                                     // E int2    (12.8 MB) alias
    size_t  o   = (size_t)N_NODES * 64 * sizeof(__half);
    float*  AGG = (float*)(wsp + o); o += (size_t)N_NODES * 64 * sizeof(float);
    int2*   csr = (int2*)(wsp + o);  o += (size_t)E_EDGES * sizeof(int2);
    int*    off = (int*)(wsp + o);   o += (size_t)(N_NODES + 1) * sizeof(int);
    int*  histM = (int*)(wsp + o);   o += (size_t)HM * sizeof(int);
    int*    hs  = (int*)(wsp + o);   o += (size_t)HM * sizeof(int);
    int*  bsums = (int*)(wsp + o);   o += (size_t)NSB * sizeof(int);
    int*   boff = (int*)(wsp + o);   o += (size_t)NSB * sizeof(int);

    dim3 blk(256);
    const int gemmGrid = (N_NODES + 63) / 64;              // 1563
    const int aggGrid  = (N_NODES * 64 + 255) / 256;       // 25000

    // ---- build CSR (once; reused by all 5 layers), zero global atomics ----
    chunk_hist<<<NCHUNK, blk, 0, stream>>>((const int4*)dst, histM);
    scan_blocks<<<NSB, blk, 0, stream>>>(histM, hs, bsums);
    scan_mid256<<<1, blk, 0, stream>>>(bsums, boff);
    scan_add<<<NSB, blk, 0, stream>>>(hs, boff);
    chunk_scatter<<<NCHUNK, blk, 0, stream>>>((const int4*)src, (const int4*)dst,
                                              (const float4*)ew, hs, tmp);
    build_csr<<<NBUCKETS, blk, 0, stream>>>(tmp, hs, off, csr);

    // ---- layer 0 ----
    gemm_tile<64, false><<<gemmGrid, blk, 0, stream>>>(x, W, H2);
    aggregate<64><<<aggGrid, blk, 0, stream>>>(H2, off, csr, b, AGG);

    // ---- layers 1..3 ----
    for (int i = 1; i < 4; ++i) {
        gemm_tile<64, true><<<gemmGrid, blk, 0, stream>>>(AGG, W + (size_t)i * 64 * 64, H2);
        aggregate<64><<<aggGrid, blk, 0, stream>>>(H2, off, csr, b + (size_t)i * 64, AGG);
    }

    // ---- final layer -> d_out [N,40] ----
    gemm_tile<40, true><<<gemmGrid, blk, 0, stream>>>(AGG, Wout, H2);
    aggregate<40><<<aggGrid, blk, 0, stream>>>(H2, off, csr, bout, out);
}